// Round 2
// baseline (1657.904 us; speedup 1.0000x reference)
//
#include <hip/hip_runtime.h>
#include <math.h>

// Problem dims
#define Bd   512
#define Sd   400
#define Vd   50000
#define Ed   512
#define Hd   256
#define EMBd 128
// xh = [context(512) | embed(128) | h0(256)] stride 896
#define XHs  896
#define Gd   1024   // 4*H

// d_out float offsets: output(B*V), new_coverage(B*S), h_t(B*H), c_t(B*H), new_attn(B*S), loss(1)
#define OFF_COV  25600000
#define OFF_H    25804800
#define OFF_C    25935872
#define OFF_ATTN 26066944
#define OFF_LOSS 26271744

// workspace float offsets
#define WS_XH     0
#define WS_GATES  458752
#define WS_WSAPP  983040
#define WS_PGEN   1114112
#define WS_ENERGY 1114624
#define WS_LOSSB  1319424
#define WS_RMAX   1319936
#define WS_RSCALE 1320448

__device__ __forceinline__ float sigmoid_f(float x){ return 1.f/(1.f + __expf(-x)); }
__device__ __forceinline__ float tanh_f(float x){ return 1.f - 2.f/(__expf(2.f*x) + 1.f); }

// ---------------- K1: context + embed gather + h0 copy into xh ----------------
__global__ __launch_bounds__(256) void k_context(
    const float* __restrict__ attn, const float* __restrict__ enc_out,
    const float* __restrict__ h0, const int* __restrict__ dec_input,
    const float* __restrict__ emb_table, float* __restrict__ xh)
{
  int b = blockIdx.x, t = threadIdx.x;
  __shared__ float sa[Sd];
  for (int s = t; s < Sd; s += 256) sa[s] = attn[(size_t)b*Sd + s];
  __syncthreads();
  const float* ep = enc_out + (size_t)b*Sd*Ed;
  float acc0 = 0.f, acc1 = 0.f;
  #pragma unroll 4
  for (int s = 0; s < Sd; ++s){
    float a = sa[s];
    acc0 += a * ep[(size_t)s*Ed + t];
    acc1 += a * ep[(size_t)s*Ed + t + 256];
  }
  float* xrow = xh + (size_t)b*XHs;
  xrow[t]       = acc0;
  xrow[t + 256] = acc1;
  if (t < EMBd){
    int tok = dec_input[b];
    xrow[Ed + t] = emb_table[(size_t)tok*EMBd + t];
  }
  xrow[Ed + EMBd + t] = h0[(size_t)b*Hd + t];
}

// ---------------- K2: gates = xh @ [W_ih|W_hh]^T + b_ih + b_hh ----------------
// tile 32 rows(b) x 64 cols(j), K=896, BK=32
__global__ __launch_bounds__(256) void k_gates(
    const float* __restrict__ xh, const float* __restrict__ W_ih,
    const float* __restrict__ W_hh, const float* __restrict__ b_ih,
    const float* __restrict__ b_hh, float* __restrict__ gates)
{
  __shared__ float Al[32*36];
  __shared__ float Wl[64*33];
  int tid = threadIdx.x;
  int col0 = blockIdx.x * 64;
  int row0 = blockIdx.y * 32;
  int cg = tid & 15, rg = tid >> 4;         // cols cg+16j (j<4), rows rg*2+i (i<2)
  float acc[2][4] = {{0,0,0,0},{0,0,0,0}};
  int alr = tid >> 3, alk = (tid & 7) * 4;  // A loader: 32r x 32k, 1 float4
  int wlj = tid >> 2, wlk = (tid & 3) * 8;  // W loader: 64j x 32k, 8 floats
  for (int kt = 0; kt < 28; ++kt){
    int k0 = kt * 32;
    float4 a4 = *(const float4*)(xh + (size_t)(row0+alr)*XHs + k0 + alk);
    *(float4*)(Al + alr*36 + alk) = a4;
    {
      const float* src;
      if (k0 < Ed + EMBd) src = W_ih + (size_t)(col0+wlj)*(Ed+EMBd) + k0 + wlk;
      else                src = W_hh + (size_t)(col0+wlj)*Hd + (k0 - (Ed+EMBd)) + wlk;
      #pragma unroll
      for (int q = 0; q < 8; ++q) Wl[wlj*33 + wlk + q] = src[q];
    }
    __syncthreads();
    #pragma unroll 4
    for (int k = 0; k < 32; ++k){
      float a0 = Al[(rg*2+0)*36 + k];
      float a1 = Al[(rg*2+1)*36 + k];
      #pragma unroll
      for (int j = 0; j < 4; ++j){
        float w = Wl[(cg + 16*j)*33 + k];
        acc[0][j] += a0 * w;
        acc[1][j] += a1 * w;
      }
    }
    __syncthreads();
  }
  #pragma unroll
  for (int i = 0; i < 2; ++i){
    int row = row0 + rg*2 + i;
    #pragma unroll
    for (int j = 0; j < 4; ++j){
      int col = col0 + cg + 16*j;
      gates[(size_t)row*Gd + col] = acc[i][j] + b_ih[col] + b_hh[col];
    }
  }
}

// ---------------- K3: LSTM cell -> h_t, c_t (into d_out) ----------------
__global__ __launch_bounds__(256) void k_lstm(
    const float* __restrict__ gates, const float* __restrict__ c0,
    float* __restrict__ dout)
{
  int idx = blockIdx.x*256 + threadIdx.x;   // B*H
  int b = idx >> 8, h = idx & 255;
  const float* g = gates + (size_t)b*Gd;
  float xi = g[h], xf = g[Hd + h], xg = g[2*Hd + h], xo = g[3*Hd + h];
  float c  = sigmoid_f(xf)*c0[idx] + sigmoid_f(xi)*tanh_f(xg);
  float ht = sigmoid_f(xo)*tanh_f(c);
  dout[OFF_C + idx] = c;
  dout[OFF_H + idx] = ht;
}

// ---------------- K4: ws_app = h_t @ aws_W^T + aws_b ----------------
__global__ __launch_bounds__(256) void k_wsapp(
    const float* __restrict__ ht, const float* __restrict__ aws_W,
    const float* __restrict__ aws_b, float* __restrict__ wsapp)
{
  int b = blockIdx.x, t = threadIdx.x;
  __shared__ float hrow[Hd];
  hrow[t] = ht[(size_t)b*Hd + t];
  __syncthreads();
  const float4* w4 = (const float4*)(aws_W + (size_t)t*Hd);
  float acc = 0.f;
  #pragma unroll 4
  for (int k4 = 0; k4 < Hd/4; ++k4){
    float4 w = w4[k4];
    int k = k4*4;
    acc += hrow[k]*w.x + hrow[k+1]*w.y + hrow[k+2]*w.z + hrow[k+3]*w.w;
  }
  wsapp[(size_t)b*Hd + t] = acc + aws_b[t];
}

// ---------------- K5: p_gen ----------------
__global__ __launch_bounds__(256) void k_pgen(
    const float* __restrict__ xh, const float* __restrict__ ht,
    const float* __restrict__ wh, const float* __restrict__ wsv,
    const float* __restrict__ wx, float* __restrict__ pgen)
{
  int b = blockIdx.x, t = threadIdx.x;
  __shared__ float red[256];
  const float* x = xh + (size_t)b*XHs;
  float part = x[t]*wh[t] + x[t+256]*wh[t+256];     // context . wh
  part += ht[(size_t)b*Hd + t] * wsv[t];            // h_t . ws
  if (t < EMBd) part += x[Ed + t] * wx[t];          // embed . wx
  red[t] = part; __syncthreads();
  for (int off = 128; off > 0; off >>= 1){
    if (t < off) red[t] += red[t + off];
    __syncthreads();
  }
  if (t == 0) pgen[b] = sigmoid_f(red[0]);
}

// ---------------- K6: fused energy GEMM + tanh + av-dot ----------------
// rows = b*S+s (204800), tile 64 rows x 256 cols(H), K=512, BK=32
__global__ __launch_bounds__(256) void k_energy(
    const float* __restrict__ enc_out, const float* __restrict__ awh_W,
    const float* __restrict__ awh_b, const float* __restrict__ wsapp,
    const float* __restrict__ coverage, const float* __restrict__ awc,
    const float* __restrict__ av, float* __restrict__ energy)
{
  __shared__ float Al[32*68];     // [k][r] stride 68 (broadcast reads)
  __shared__ float Wl[32*258];    // [k][h] stride 258 (2-way = free)
  __shared__ float red[64*33];
  int tid = threadIdx.x;
  int row0 = blockIdx.x * 64;
  int cg = tid & 31, rg = tid >> 5;        // cols: cg*2+jj+64j, rows: rg*8+i
  float acc[8][8];
  #pragma unroll
  for (int i=0;i<8;++i){
    #pragma unroll
    for (int j=0;j<8;++j) acc[i][j]=0.f;
  }
  int alr = tid >> 2, alk = (tid & 3) * 8;
  int wlh = tid >> 3, wlk = (tid & 7) * 4;
  for (int kt = 0; kt < Ed/32; ++kt){
    int k0 = kt * 32;
    const float* ap = enc_out + (size_t)(row0 + alr)*Ed + k0 + alk;
    float4 x0 = *(const float4*)ap;
    float4 x1 = *(const float4*)(ap + 4);
    Al[(alk+0)*68 + alr] = x0.x; Al[(alk+1)*68 + alr] = x0.y;
    Al[(alk+2)*68 + alr] = x0.z; Al[(alk+3)*68 + alr] = x0.w;
    Al[(alk+4)*68 + alr] = x1.x; Al[(alk+5)*68 + alr] = x1.y;
    Al[(alk+6)*68 + alr] = x1.z; Al[(alk+7)*68 + alr] = x1.w;
    #pragma unroll
    for (int p = 0; p < 8; ++p){
      int h = wlh + 32*p;
      float4 w4 = *(const float4*)(awh_W + (size_t)h*Ed + k0 + wlk);
      Wl[(wlk+0)*258 + h] = w4.x; Wl[(wlk+1)*258 + h] = w4.y;
      Wl[(wlk+2)*258 + h] = w4.z; Wl[(wlk+3)*258 + h] = w4.w;
    }
    __syncthreads();
    #pragma unroll 4
    for (int k = 0; k < 32; ++k){
      float a[8], w[8];
      *(float4*)(&a[0]) = *(const float4*)(Al + k*68 + rg*8);
      *(float4*)(&a[4]) = *(const float4*)(Al + k*68 + rg*8 + 4);
      #pragma unroll
      for (int j = 0; j < 4; ++j){
        float2 w2 = *(const float2*)(Wl + k*258 + cg*2 + 64*j);
        w[2*j] = w2.x; w[2*j+1] = w2.y;
      }
      #pragma unroll
      for (int i = 0; i < 8; ++i){
        #pragma unroll
        for (int j = 0; j < 8; ++j) acc[i][j] += a[i]*w[j];
      }
    }
    __syncthreads();
  }
  #pragma unroll
  for (int i = 0; i < 8; ++i){
    int grow = row0 + rg*8 + i;
    int b = grow / Sd, s = grow - b*Sd;
    float cov = coverage[(size_t)b*Sd + s];
    const float* wsp = wsapp + (size_t)b*Hd;
    float part = 0.f;
    #pragma unroll
    for (int j = 0; j < 4; ++j){
      #pragma unroll
      for (int jj = 0; jj < 2; ++jj){
        int h = cg*2 + jj + 64*j;
        float tv = acc[i][2*j+jj] + awh_b[h] + wsp[h] + cov*awc[h];
        part += av[h]*tanh_f(tv);
      }
    }
    red[(rg*8+i)*33 + cg] = part;
  }
  __syncthreads();
  if (tid < 64){
    float s = 0.f;
    #pragma unroll
    for (int c = 0; c < 32; ++c) s += red[tid*33 + c];
    energy[row0 + tid] = s;
  }
}

// ---------------- K7: attn softmax + new_coverage + per-b loss ----------------
__global__ __launch_bounds__(256) void k_attn_softmax(
    const float* __restrict__ energy, const float* __restrict__ coverage,
    float* __restrict__ dout, float* __restrict__ loss_b)
{
  int b = blockIdx.x, t = threadIdx.x;
  __shared__ float red[256];
  const float* e = energy + (size_t)b*Sd;
  float e0 = e[t];
  float e1 = (t + 256 < Sd) ? e[t+256] : -1e30f;
  red[t] = fmaxf(e0, e1); __syncthreads();
  for (int off = 128; off > 0; off >>= 1){
    if (t < off) red[t] = fmaxf(red[t], red[t+off]);
    __syncthreads();
  }
  float m = red[0]; __syncthreads();
  float p0 = __expf(e0 - m);
  float p1 = (t + 256 < Sd) ? __expf(e1 - m) : 0.f;
  red[t] = p0 + p1; __syncthreads();
  for (int off = 128; off > 0; off >>= 1){
    if (t < off) red[t] += red[t+off];
    __syncthreads();
  }
  float inv = 1.f / red[0]; __syncthreads();
  float* attn_o = dout + OFF_ATTN + (size_t)b*Sd;
  float* cov_o  = dout + OFF_COV  + (size_t)b*Sd;
  float a0 = p0 * inv;
  float cv0 = coverage[(size_t)b*Sd + t];
  attn_o[t] = a0; cov_o[t] = cv0 + a0;
  float lp = fminf(a0, cv0);
  if (t + 256 < Sd){
    float a1 = p1 * inv;
    float cv1 = coverage[(size_t)b*Sd + t + 256];
    attn_o[t+256] = a1; cov_o[t+256] = cv1 + a1;
    lp += fminf(a1, cv1);
  }
  red[t] = lp; __syncthreads();
  for (int off = 128; off > 0; off >>= 1){
    if (t < off) red[t] += red[t+off];
    __syncthreads();
  }
  if (t == 0) loss_b[b] = red[0];
}

__global__ void k_loss(const float* __restrict__ loss_b, float* __restrict__ dout)
{
  __shared__ float red[256];
  int t = threadIdx.x;
  red[t] = loss_b[t] + loss_b[t + 256];
  __syncthreads();
  for (int off = 128; off > 0; off >>= 1){
    if (t < off) red[t] += red[t+off];
    __syncthreads();
  }
  if (t == 0) dout[OFF_LOSS] = red[0];
}

// ---------------- K8: logits = h_t @ v_W^T + v_b (into d_out[0:B*V]) ----------------
// tile 64 rows(b) x 256 cols(v), K=256, BK=32
__global__ __launch_bounds__(256) void k_logits(
    const float* __restrict__ ht, const float* __restrict__ v_W,
    const float* __restrict__ v_b, float* __restrict__ out)
{
  __shared__ float Al[32*68];
  __shared__ float Wl[32*258];
  int tid = threadIdx.x;
  int col0 = blockIdx.x * 256;
  int row0 = blockIdx.y * 64;
  int cg = tid & 31, rg = tid >> 5;
  float acc[8][8];
  #pragma unroll
  for (int i=0;i<8;++i){
    #pragma unroll
    for (int j=0;j<8;++j) acc[i][j]=0.f;
  }
  int alr = tid >> 2, alk = (tid & 3) * 8;
  int wlh = tid >> 3, wlk = (tid & 7) * 4;
  for (int kt = 0; kt < Hd/32; ++kt){
    int k0 = kt * 32;
    const float* ap = ht + (size_t)(row0 + alr)*Hd + k0 + alk;
    float4 x0 = *(const float4*)ap;
    float4 x1 = *(const float4*)(ap + 4);
    Al[(alk+0)*68 + alr] = x0.x; Al[(alk+1)*68 + alr] = x0.y;
    Al[(alk+2)*68 + alr] = x0.z; Al[(alk+3)*68 + alr] = x0.w;
    Al[(alk+4)*68 + alr] = x1.x; Al[(alk+5)*68 + alr] = x1.y;
    Al[(alk+6)*68 + alr] = x1.z; Al[(alk+7)*68 + alr] = x1.w;
    #pragma unroll
    for (int p = 0; p < 8; ++p){
      int h = wlh + 32*p;
      int v = col0 + h; if (v > Vd-1) v = Vd-1;
      float4 w4 = *(const float4*)(v_W + (size_t)v*Hd + k0 + wlk);
      Wl[(wlk+0)*258 + h] = w4.x; Wl[(wlk+1)*258 + h] = w4.y;
      Wl[(wlk+2)*258 + h] = w4.z; Wl[(wlk+3)*258 + h] = w4.w;
    }
    __syncthreads();
    #pragma unroll 4
    for (int k = 0; k < 32; ++k){
      float a[8], w[8];
      *(float4*)(&a[0]) = *(const float4*)(Al + k*68 + rg*8);
      *(float4*)(&a[4]) = *(const float4*)(Al + k*68 + rg*8 + 4);
      #pragma unroll
      for (int j = 0; j < 4; ++j){
        float2 w2 = *(const float2*)(Wl + k*258 + cg*2 + 64*j);
        w[2*j] = w2.x; w[2*j+1] = w2.y;
      }
      #pragma unroll
      for (int i = 0; i < 8; ++i){
        #pragma unroll
        for (int j = 0; j < 8; ++j) acc[i][j] += a[i]*w[j];
      }
    }
    __syncthreads();
  }
  #pragma unroll
  for (int i = 0; i < 8; ++i){
    int row = row0 + rg*8 + i;
    float* orow = out + (size_t)row*Vd;
    #pragma unroll
    for (int j = 0; j < 4; ++j){
      int v0 = col0 + cg*2 + 64*j;
      if (v0 < Vd){
        float2 r;
        r.x = acc[i][2*j]   + v_b[v0];
        r.y = acc[i][2*j+1] + v_b[v0+1];
        *(float2*)(orow + v0) = r;
      }
    }
  }
}

// ---------------- K9: per-row vocab max & scale ----------------
__global__ __launch_bounds__(256) void k_vocab_stats(
    const float* __restrict__ logits, const float* __restrict__ pgen,
    float* __restrict__ rmax, float* __restrict__ rscale)
{
  int b = blockIdx.x, t = threadIdx.x;
  __shared__ float red[256];
  const float4* row = (const float4*)(logits + (size_t)b*Vd);
  float m = -1e30f;
  for (int i = t; i < Vd/4; i += 256){
    float4 x = row[i];
    m = fmaxf(m, fmaxf(fmaxf(x.x, x.y), fmaxf(x.z, x.w)));
  }
  red[t] = m; __syncthreads();
  for (int off = 128; off > 0; off >>= 1){
    if (t < off) red[t] = fmaxf(red[t], red[t+off]);
    __syncthreads();
  }
  m = red[0]; __syncthreads();
  float s = 0.f;
  for (int i = t; i < Vd/4; i += 256){
    float4 x = row[i];
    s += __expf(x.x-m) + __expf(x.y-m) + __expf(x.z-m) + __expf(x.w-m);
  }
  red[t] = s; __syncthreads();
  for (int off = 128; off > 0; off >>= 1){
    if (t < off) red[t] += red[t+off];
    __syncthreads();
  }
  if (t == 0){ rmax[b] = m; rscale[b] = pgen[b] / red[0]; }
}

// ---------------- K10: normalize logits -> p_gen * p_vocab ----------------
__global__ __launch_bounds__(256) void k_vocab_norm(
    float* __restrict__ out, const float* __restrict__ rmax,
    const float* __restrict__ rscale)
{
  long long i4 = (long long)blockIdx.x*256 + threadIdx.x;  // exactly B*V/4 threads
  int b = (int)(i4 / (Vd/4));
  float m = rmax[b], sc = rscale[b];
  float4* o = (float4*)out;
  float4 x = o[i4];
  x.x = sc*__expf(x.x - m); x.y = sc*__expf(x.y - m);
  x.z = sc*__expf(x.z - m); x.w = sc*__expf(x.w - m);
  o[i4] = x;
}

// ---------------- K11: scatter-add of (1-p_gen)*new_attn with .set semantics ----------------
__global__ __launch_bounds__(256) void k_scatter(
    const int* __restrict__ enc_inputs, const float* __restrict__ pgen,
    float* __restrict__ dout)
{
  int idx = blockIdx.x*256 + threadIdx.x;    // B*S
  int b = idx / Sd, s = idx - b*Sd;
  const int* row = enc_inputs + (size_t)b*Sd;
  int v = row[s];
  // last-write-wins: only the last occurrence of v in this row writes
  for (int s2 = s+1; s2 < Sd; ++s2) if (row[s2] == v) return;
  float pg = pgen[b];
  float a = dout[OFF_ATTN + idx];
  float* p = dout + (size_t)b*Vd + v;
  *p = *p + (1.f - pg)*a;
}

extern "C" void kernel_launch(void* const* d_in, const int* in_sizes, int n_in,
                              void* d_out, int out_size, void* d_ws, size_t ws_size,
                              hipStream_t stream)
{
  const float* coverage   = (const float*)d_in[0];
  const float* enc_out    = (const float*)d_in[1];
  const float* h0         = (const float*)d_in[2];
  const float* c0         = (const float*)d_in[3];
  const float* attn       = (const float*)d_in[4];
  const int*   dec_input  = (const int*)  d_in[5];
  const int*   enc_inputs = (const int*)  d_in[6];
  const float* emb_table  = (const float*)d_in[7];
  const float* W_ih       = (const float*)d_in[8];
  const float* W_hh       = (const float*)d_in[9];
  const float* b_ih       = (const float*)d_in[10];
  const float* b_hh       = (const float*)d_in[11];
  const float* awh_W      = (const float*)d_in[12];
  const float* awh_b      = (const float*)d_in[13];
  const float* aws_W      = (const float*)d_in[14];
  const float* aws_b      = (const float*)d_in[15];
  const float* awc        = (const float*)d_in[16];
  const float* av         = (const float*)d_in[17];
  const float* wh         = (const float*)d_in[18];
  const float* wsv        = (const float*)d_in[19];
  const float* wx         = (const float*)d_in[20];
  const float* v_W        = (const float*)d_in[21];
  const float* v_b        = (const float*)d_in[22];
  float* out = (float*)d_out;
  float* ws  = (float*)d_ws;

  float* xh     = ws + WS_XH;
  float* gates  = ws + WS_GATES;
  float* wsapp  = ws + WS_WSAPP;
  float* pgen   = ws + WS_PGEN;
  float* energy = ws + WS_ENERGY;
  float* loss_b = ws + WS_LOSSB;
  float* rmax   = ws + WS_RMAX;
  float* rscale = ws + WS_RSCALE;
  float* ht = out + OFF_H;

  k_context<<<Bd, 256, 0, stream>>>(attn, enc_out, h0, dec_input, emb_table, xh);
  k_gates<<<dim3(Gd/64, Bd/32), 256, 0, stream>>>(xh, W_ih, W_hh, b_ih, b_hh, gates);
  k_lstm<<<(Bd*Hd)/256, 256, 0, stream>>>(gates, c0, out);
  k_wsapp<<<Bd, 256, 0, stream>>>(ht, aws_W, aws_b, wsapp);
  k_pgen<<<Bd, 256, 0, stream>>>(xh, ht, wh, wsv, wx, pgen);
  k_energy<<<(Bd*Sd)/64, 256, 0, stream>>>(enc_out, awh_W, awh_b, wsapp, coverage, awc, av, energy);
  k_attn_softmax<<<Bd, 256, 0, stream>>>(energy, coverage, out, loss_b);
  k_loss<<<1, 256, 0, stream>>>(loss_b, out);
  k_logits<<<dim3((Vd + 255)/256, Bd/64), 256, 0, stream>>>(ht, v_W, v_b, out);
  k_vocab_stats<<<Bd, 256, 0, stream>>>(out, pgen, rmax, rscale);
  k_vocab_norm<<<(Bd*Vd/4)/256, 256, 0, stream>>>(out, rmax, rscale);
  k_scatter<<<(Bd*Sd)/256, 256, 0, stream>>>(enc_inputs, pgen, out);
}